// Round 8
// baseline (1608.017 us; speedup 1.0000x reference)
//
#include <hip/hip_runtime.h>
#include <math.h>

// GRU-RCN bf16 MFMA. B=8,T=16,C=Oh=64,HxW=56x56, 3x3 SAME.
// Round-8: stage strips ONCE per block, loop all channel slices inside
// (4x less strip traffic, 4x MFMA per block); 4-deep B prefetch (static
// buffers, fully unrolled phases); XCD-affine grid (b = bid&7).
// Per step t: stepA -> z (fp16), r*h (bf16 padded); stepB -> h', out (+xprep).
// Layouts:
//   padded imgs (xpad[2]/hpad/rhpad): bf16 [b][58][66][64ci], 16B ci-slices
//     XOR-swizzled by (col&7) -> conflict-free ds_read_b128.
//   wcat: bf16 [plane(ky*3+kx)][o][ci] (W:192ch, U:128ch, C:64ch)
//   zbuf: fp16 [b][y][px64][64]; hstate: f32 [b][y][px64][64]

#define PIX 4224                   // 66*64 u16 per padded row
#define PIMG 244992                // 58*PIX u16 per padded image
#define BIMG ((size_t)8 * PIMG)    // u16 per image set (8 batches)
#define HL_OFF ((size_t)25690112)  // 8*16*64*3136 floats
#define STRIP 13056                // u16 per staged 6-row strip (6*34*64)

typedef unsigned short u16;
typedef __attribute__((ext_vector_type(8))) __bf16 bf16x8;
typedef __attribute__((ext_vector_type(4))) float f32x4;

__device__ __forceinline__ float bf2f(u16 u) {
  unsigned v = ((unsigned)u) << 16;
  float f;
  __builtin_memcpy(&f, &v, 4);
  return f;
}
__device__ __forceinline__ u16 f2bf(float f) {
  unsigned u;
  __builtin_memcpy(&u, &f, 4);
  u = (u + 0x7FFFu + ((u >> 16) & 1u)) >> 16;  // RNE
  return (u16)u;
}
__device__ __forceinline__ void gll16(const void* g, void* l) {
  __builtin_amdgcn_global_load_lds(
      (const __attribute__((address_space(1))) void*)g,
      (__attribute__((address_space(3))) void*)l, 16, 0, 0);
}

// ---- B-fragment load: 3kx x NF bf16x8 for one (source, p6) phase -----------
template <int NF>
__device__ __forceinline__ void loadB(const u16* wr, int NCH, int p6,
                                      bf16x8 (&buf)[3][NF]) {
  const int ky = p6 >> 1, kc = p6 & 1;
#pragma unroll
  for (int kx = 0; kx < 3; ++kx)
#pragma unroll
    for (int nf = 0; nf < NF; ++nf)
      buf[kx][nf] = *(const bf16x8*)(wr + (size_t)((ky * 3 + kx) * NCH) * 64 +
                                     nf * 1024 + kc * 32);
}

// ---- one phase: 6 ds_read_b128 + 3*2*NF MFMA + prefetch into just-used buf --
#define DO_PHASE(P, BUF, PW, PP6, PNCH)                                        \
  {                                                                            \
    constexpr int ky = ((P) % 6) >> 1;                                         \
    constexpr int kc = (P) & 1;                                                \
    constexpr int soff = ((P) < 6) ? 0 : STRIP;                                \
    bf16x8 af[2][3];                                                           \
    _Pragma("unroll") for (int mf = 0; mf < 2; ++mf)                           \
        _Pragma("unroll") for (int kx = 0; kx < 3; ++kx) {                     \
      const int pp = mf * 16 + (lane & 15) + kx;                               \
      const int sl = (kc * 4 + (lane >> 4)) ^ (pp & 7);                        \
      af[mf][kx] = *(const bf16x8*)(stage + soff +                             \
                                    ((wv + ky) * 34 + pp) * 64 + sl * 8);      \
    }                                                                          \
    _Pragma("unroll") for (int kx = 0; kx < 3; ++kx)                           \
        _Pragma("unroll") for (int mf = 0; mf < 2; ++mf)                       \
            _Pragma("unroll") for (int nf = 0; nf < NF; ++nf)                  \
                acc[mf][nf] = __builtin_amdgcn_mfma_f32_16x16x32_bf16(         \
                    af[mf][kx], BUF[kx][nf], acc[mf][nf], 0, 0, 0);            \
    if (PW) loadB<NF>(PW, PNCH, PP6, BUF);                                     \
  }

// 12 phases (src0 p0-5, src1 p0-5); on entry B0..B3 hold phases 0..3; on exit
// they hold next-s phases 0..3 (prefetched via nwr0, or stale if nwr0==null).
template <int NF>
__device__ __forceinline__ void run12(const u16* stage, const u16* wr0,
                                      const u16* wr1, int NCH0, int NCH1,
                                      const u16* nwr0, bf16x8 (&B0)[3][NF],
                                      bf16x8 (&B1)[3][NF], bf16x8 (&B2)[3][NF],
                                      bf16x8 (&B3)[3][NF], f32x4 (&acc)[2][NF],
                                      int lane, int wv) {
  DO_PHASE(0, B0, wr0, 4, NCH0)
  DO_PHASE(1, B1, wr0, 5, NCH0)
  DO_PHASE(2, B2, wr1, 0, NCH1)
  DO_PHASE(3, B3, wr1, 1, NCH1)
  DO_PHASE(4, B0, wr1, 2, NCH1)
  DO_PHASE(5, B1, wr1, 3, NCH1)
  DO_PHASE(6, B2, wr1, 4, NCH1)
  DO_PHASE(7, B3, wr1, 5, NCH1)
  DO_PHASE(8, B0, nwr0, 0, NCH0)
  DO_PHASE(9, B1, nwr0, 1, NCH0)
  DO_PHASE(10, B2, nwr0, 2, NCH0)
  DO_PHASE(11, B3, nwr0, 3, NCH0)
}

// ---- stage both 6-row strips (34px x 128B rows) -----------------------------
__device__ __forceinline__ void stage2(const u16* img0, const u16* img1,
                                       int y0, int x0, u16* stage, int lane,
                                       int wv) {
  for (int i = wv; i < 60; i += 4) {
    const int sp = i / 30, j = i % 30, r = j / 5, k = j % 5;
    const u16* g = (sp ? img1 : img0) + (size_t)(y0 + r) * PIX + x0 * 64 +
                   k * 512 + lane * 8;
    u16* l = stage + sp * STRIP + r * 2176 + k * 512;
    if (k < 4 || lane < 16) gll16(g, l);
  }
}

// ---- prep -------------------------------------------------------------------
__global__ __launch_bounds__(256) void wprep_k(const float* __restrict__ W,
                                               const float* __restrict__ U,
                                               const float* __restrict__ C,
                                               u16* __restrict__ wcat) {
  int i = blockIdx.x * 256 + threadIdx.x;
  if (i >= 221184) return;
  float v;
  if (i < 110592) {
    int plane = i / 12288, rem = i % 12288, o = rem / 64, ci = rem % 64;
    v = W[(size_t)(o * 64 + ci) * 9 + plane];
  } else if (i < 184320) {
    int j = i - 110592;
    int plane = j / 8192, rem = j % 8192, o = rem / 64, ci = rem % 64;
    v = U[(size_t)(o * 64 + ci) * 9 + plane];
  } else {
    int j = i - 184320;
    int plane = j / 4096, rem = j % 4096, o = rem / 64, ci = rem % 64;
    v = C[(size_t)(o * 64 + ci) * 9 + plane];
  }
  wcat[i] = f2bf(v);
}

__global__ __launch_bounds__(256) void hinit_k(const float* __restrict__ h,
                                               u16* __restrict__ hpad,
                                               float* __restrict__ hstate) {
  __shared__ float t[64][57];
  const int y = blockIdx.x, b = blockIdx.y;
  const int tid = threadIdx.x;
  for (int i = tid; i < 64 * 56; i += 256) {
    int ci = i / 56, xx = i % 56;
    t[ci][xx] = h[((size_t)(b * 64) + ci) * 3136 + y * 56 + xx];
  }
  __syncthreads();
  const size_t pb = (size_t)b * PIMG + (size_t)(y + 1) * PIX;
  const size_t sb = ((size_t)(b * 56) + y) * 64;
  for (int i = tid; i < 56 * 64; i += 256) {
    int px = i / 64, ci = i % 64;
    float v = t[ci][px];
    int gx = px + 1;
    hpad[pb + gx * 64 + (((ci >> 3) ^ (gx & 7)) << 3) + (ci & 7)] = f2bf(v);
    hstate[(sb + px) * 64 + ci] = v;
  }
}

__device__ __forceinline__ void xprep_row(const float* __restrict__ x,
                                          u16* __restrict__ dst, int t, int b,
                                          int y, float (*tx)[57]) {
  const int tid = threadIdx.x;
  for (int i = tid; i < 64 * 56; i += 256) {
    int ci = i / 56, px = i % 56;
    tx[ci][px] = x[((size_t)(b * 16 + t) * 64 + ci) * 3136 + y * 56 + px];
  }
  __syncthreads();
  const size_t pb = (size_t)b * PIMG + (size_t)(y + 1) * PIX;
  for (int i = tid; i < 56 * 64; i += 256) {
    int px = i / 64, ci = i % 64;
    int gx = px + 1;
    dst[pb + gx * 64 + (((ci >> 3) ^ (gx & 7)) << 3) + (ci & 7)] =
        f2bf(tx[ci][px]);
  }
}

__global__ __launch_bounds__(256) void xprep0_k(const float* __restrict__ x,
                                                u16* __restrict__ xpad) {
  __shared__ float tt[64][57];
  xprep_row(x, xpad, 0, blockIdx.x & 7, blockIdx.x >> 3, tt);
}

// ---- stepA: z (s=0,1) & r*h (s=2,3); 224 blocks, b=bid&7 -------------------
__global__ __launch_bounds__(256, 1) void stepA_k(
    const u16* __restrict__ xpad, const u16* __restrict__ hpad,
    const u16* __restrict__ wcat, _Float16* __restrict__ zbuf,
    u16* __restrict__ rhpad) {
  __shared__ __align__(16) u16 stage[2 * STRIP];
  const int bid = blockIdx.x;
  const int b = bid & 7, unit = bid >> 3;      // 28 units/batch
  const int x0 = (unit & 1) * 32, y0 = (unit >> 1) * 4;
  const int lane = threadIdx.x & 63, wv = threadIdx.x >> 6;
  const int laneoff = (lane & 15) * 64 + (lane >> 4) * 8;

  stage2(xpad + (size_t)b * PIMG, hpad + (size_t)b * PIMG, y0, x0, stage, lane,
         wv);

  const u16* w0 = wcat + laneoff;           // W (NCH=192), ch 0..127 used
  const u16* w1 = wcat + 110592 + laneoff;  // U (NCH=128)
  bf16x8 B0[3][2], B1[3][2], B2[3][2], B3[3][2];
  loadB<2>(w0, 192, 0, B0);
  loadB<2>(w0, 192, 1, B1);
  loadB<2>(w0, 192, 2, B2);
  loadB<2>(w0, 192, 3, B3);
  asm volatile("s_waitcnt vmcnt(0)" ::: "memory");
  __syncthreads();

  const int y = y0 + wv;
  const size_t rowb = ((size_t)(b * 56) + y) * 64;

#pragma unroll 1
  for (int s = 0; s < 4; ++s) {
    f32x4 acc[2][2];
#pragma unroll
    for (int mf = 0; mf < 2; ++mf)
#pragma unroll
      for (int nf = 0; nf < 2; ++nf) acc[mf][nf] = (f32x4){0.f, 0.f, 0.f, 0.f};

    const u16* wr0 = w0 + s * 2048;
    const u16* wr1 = w1 + s * 2048;
    const u16* nwr0 = (s < 3) ? (w0 + (s + 1) * 2048) : (const u16*)0;
    run12<2>(stage, wr0, wr1, 192, 128, nwr0, B0, B1, B2, B3, acc, lane, wv);

#pragma unroll
    for (int mf = 0; mf < 2; ++mf)
#pragma unroll
      for (int nf = 0; nf < 2; ++nf) {
        const int nl = nf * 16 + (lane & 15);
#pragma unroll
        for (int r = 0; r < 4; ++r) {
          const int px = x0 + mf * 16 + 4 * (lane >> 4) + r;
          if (px < 56) {
            const float sg = 1.f / (1.f + __expf(-acc[mf][nf][r]));
            if (s < 2) {
              zbuf[(rowb + px) * 64 + s * 32 + nl] = (_Float16)sg;
            } else {
              const int ci = (s - 2) * 32 + nl;
              const int cp = mf * 16 + 4 * (lane >> 4) + r + 1;  // strip col
              const float hv =
                  bf2f(stage[STRIP + ((wv + 1) * 34 + cp) * 64 +
                             (((ci >> 3) ^ (cp & 7)) << 3) + (ci & 7)]);
              const int gx = px + 1;
              rhpad[(size_t)b * PIMG + (size_t)(y + 1) * PIX + gx * 64 +
                    (((ci >> 3) ^ (gx & 7)) << 3) + (ci & 7)] = f2bf(sg * hv);
            }
          }
        }
      }
  }
}

// ---- stepB: h' = (1-z)h + z tanh(conv(x,Wc)+conv(rh,C)); + xprep(t+1) ------
__global__ __launch_bounds__(256, 1) void stepB_k(
    const float* __restrict__ x, u16* __restrict__ xpad_nxt,
    const u16* __restrict__ xpad_cur, const u16* __restrict__ rhpad,
    const u16* __restrict__ wcat, const _Float16* __restrict__ zbuf,
    float* __restrict__ hstate, u16* __restrict__ hpad,
    float* __restrict__ out, int t) {
  __shared__ __align__(16) u16 stage[2 * STRIP];
  __shared__ float ldt[4][16][33];
  const int bid = blockIdx.x;
  if (bid >= 224) {  // xprep role for t+1
    const int row = bid - 224;
    xprep_row(x, xpad_nxt, t + 1, row & 7, row >> 3, (float(*)[57])stage);
    return;
  }
  const int b = bid & 7, unit = bid >> 3;
  const int x0 = (unit & 1) * 32, y0 = (unit >> 1) * 4;
  const int lane = threadIdx.x & 63, wv = threadIdx.x >> 6;
  const int laneoff = (lane & 15) * 64 + (lane >> 4) * 8;

  stage2(xpad_cur + (size_t)b * PIMG, rhpad + (size_t)b * PIMG, y0, x0, stage,
         lane, wv);

  const u16* w0 = wcat + 8192 + laneoff;    // Wc = W ch 128.. (NCH=192)
  const u16* w1 = wcat + 184320 + laneoff;  // C (NCH=64)
  bf16x8 B0[3][2], B1[3][2], B2[3][2], B3[3][2];
  loadB<2>(w0, 192, 0, B0);
  loadB<2>(w0, 192, 1, B1);
  loadB<2>(w0, 192, 2, B2);
  loadB<2>(w0, 192, 3, B3);
  asm volatile("s_waitcnt vmcnt(0)" ::: "memory");
  __syncthreads();

  const int y = y0 + wv;
  const size_t rowb = ((size_t)(b * 56) + y) * 64;

#pragma unroll 1
  for (int s = 0; s < 2; ++s) {
    f32x4 acc[2][2];
#pragma unroll
    for (int mf = 0; mf < 2; ++mf)
#pragma unroll
      for (int nf = 0; nf < 2; ++nf) acc[mf][nf] = (f32x4){0.f, 0.f, 0.f, 0.f};

    const u16* wr0 = w0 + s * 2048;
    const u16* wr1 = w1 + s * 2048;
    const u16* nwr0 = (s < 1) ? (w0 + 2048) : (const u16*)0;
    run12<2>(stage, wr0, wr1, 192, 64, nwr0, B0, B1, B2, B3, acc, lane, wv);

    float hnv[2][2][4];
#pragma unroll
    for (int mf = 0; mf < 2; ++mf)
#pragma unroll
      for (int nf = 0; nf < 2; ++nf) {
        const int n = s * 32 + nf * 16 + (lane & 15);
#pragma unroll
        for (int r = 0; r < 4; ++r) {
          const int px = x0 + mf * 16 + 4 * (lane >> 4) + r;
          hnv[mf][nf][r] = 0.f;
          if (px < 56) {
            const float htil = tanhf(acc[mf][nf][r]);
            const float z = (float)zbuf[(rowb + px) * 64 + n];
            const float ho = hstate[(rowb + px) * 64 + n];
            const float hn = fmaf(z, htil - ho, ho);
            hstate[(rowb + px) * 64 + n] = hn;
            const int gx = px + 1;
            hpad[(size_t)b * PIMG + (size_t)(y + 1) * PIX + gx * 64 +
                 (((n >> 3) ^ (gx & 7)) << 3) + (n & 7)] = f2bf(hn);
            hnv[mf][nf][r] = hn;
          }
        }
      }
    // NHWC->NCHW transpose per 16-ch group (ldt is wave-private)
#pragma unroll 1
    for (int nf = 0; nf < 2; ++nf) {
      __syncthreads();
#pragma unroll
      for (int mf = 0; mf < 2; ++mf)
#pragma unroll
        for (int r = 0; r < 4; ++r)
          ldt[wv][lane & 15][mf * 16 + 4 * (lane >> 4) + r] = hnv[mf][nf][r];
      __syncthreads();
      const int xl = lane & 31;
      const int px = x0 + xl;
      if (px < 56) {
#pragma unroll
        for (int cc = 0; cc < 8; ++cc) {
          const int ch = (lane >> 5) * 8 + cc;
          const float v = ldt[wv][ch][xl];
          const int oc = s * 32 + nf * 16 + ch;
          out[(((size_t)(b * 16 + t)) * 64 + oc) * 3136 + y * 56 + px] = v;
          if (t == 15)
            out[HL_OFF + ((size_t)(b * 64) + oc) * 3136 + y * 56 + px] = v;
        }
      }
    }
  }
}

extern "C" void kernel_launch(void* const* d_in, const int* in_sizes, int n_in,
                              void* d_out, int out_size, void* d_ws,
                              size_t ws_size, hipStream_t stream) {
  const float* x = (const float*)d_in[0];
  const float* h = (const float*)d_in[1];
  const float* W = (const float*)d_in[2];
  const float* U = (const float*)d_in[3];
  const float* C = (const float*)d_in[4];
  float* out = (float*)d_out;

  u16* ws_u = (u16*)d_ws;
  u16* xpad = ws_u;                             // 2 slots x BIMG
  u16* hpad = xpad + 2 * BIMG;                  // BIMG
  u16* rhpad = hpad + BIMG;                     // BIMG
  u16* wcat = rhpad + BIMG;                     // 221,184
  _Float16* zbuf = (_Float16*)(wcat + 221184);  // 1,835,008 fp16
  float* hstate = (float*)(zbuf + 1835008);     // 1,835,008 f32 (~27 MB total)

  // zero the 4 padded images (borders must stay 0)
  hipMemsetAsync(d_ws, 0, (size_t)4 * BIMG * sizeof(u16), stream);
  wprep_k<<<864, 256, 0, stream>>>(W, U, C, wcat);
  hinit_k<<<dim3(56, 8), 256, 0, stream>>>(h, hpad, hstate);
  xprep0_k<<<448, 256, 0, stream>>>(x, xpad);  // t=0 -> slot 0

  for (int t = 0; t < 16; ++t) {
    stepA_k<<<224, 256, 0, stream>>>(xpad + (size_t)(t & 1) * BIMG, hpad, wcat,
                                     zbuf, rhpad);
    const int nb = (t < 15) ? 672 : 224;
    stepB_k<<<nb, 256, 0, stream>>>(x, xpad + (size_t)((t + 1) & 1) * BIMG,
                                    xpad + (size_t)(t & 1) * BIMG, rhpad, wcat,
                                    zbuf, hstate, hpad, out, t);
  }
}

// Round 9
// 1204.552 us; speedup vs baseline: 1.3349x; 1.3349x over previous
//
#include <hip/hip_runtime.h>
#include <math.h>

// GRU-RCN bf16 MFMA, multi-kernel (round-5 skeleton + depth-3 B prefetch).
// B=8,T=16,C=Oh=64,HxW=56x56, 3x3 SAME.
// Structure: x-path batched per 4-timestep group:
//   per group g: convW4 (wx ring; 3584 conv blocks + 1792 xprep(g+1) blocks);
//   then 4x { convU(t): z, r*h ; convC(t): h_new, out }.
// conv core: 6 phases (ky x kc), depth-3 weight prefetch (B preloads issued
// before the strip-stage wait; distance 3 phases > L2 latency).
// Layouts:
//   padded imgs: bf16 [58][66][64ci], 16B ci-slices XOR-swizzled by (col&7).
//   xring: [slot4][b][PIMG]; wx ring: bf16 [b][slot4][y56][px64][192]
//   wcat: bf16 [plane(ky*3+kx)][o][ci] (W:192, U:128, C:64)
//   zb, hstate: f32 [b][y][px64][64]

#define PIX 4224                   // 66*64 u16 per padded row
#define PIMG 244992                // 58*PIX u16 per padded image
#define BIMG ((size_t)8 * PIMG)    // u16 per slot (8 batches)
#define HL_OFF ((size_t)25690112)  // 8*16*64*3136 floats

typedef unsigned short u16;
typedef __attribute__((ext_vector_type(8))) __bf16 bf16x8;
typedef __attribute__((ext_vector_type(4))) float f32x4;

__device__ __forceinline__ float bf2f(u16 u) {
  unsigned v = ((unsigned)u) << 16;
  float f;
  __builtin_memcpy(&f, &v, 4);
  return f;
}
__device__ __forceinline__ u16 f2bf(float f) {
  unsigned u;
  __builtin_memcpy(&u, &f, 4);
  u = (u + 0x7FFFu + ((u >> 16) & 1u)) >> 16;  // RNE
  return (u16)u;
}
__device__ __forceinline__ void gll16(const void* g, void* l) {
  __builtin_amdgcn_global_load_lds(
      (const __attribute__((address_space(1))) void*)g,
      (__attribute__((address_space(3))) void*)l, 16, 0, 0);
}

// ---- B-fragment load for phase p6 (ky=p6>>1, kc=p6&1) ----------------------
template <int NF>
__device__ __forceinline__ void loadB(const u16* wr, int NCH, int p6,
                                      bf16x8 (&buf)[3][NF]) {
  const int ky = p6 >> 1, kc = p6 & 1;
#pragma unroll
  for (int kx = 0; kx < 3; ++kx)
#pragma unroll
    for (int nf = 0; nf < NF; ++nf)
      buf[kx][nf] = *(const bf16x8*)(wr + (size_t)((ky * 3 + kx) * NCH) * 64 +
                                     nf * 1024 + kc * 32);
}

// ---- one phase: 6 ds_read_b128 + 3*2*NF MFMA, then refill the used buffer --
#define DO_P(P, BUF, PW, PP6)                                                  \
  {                                                                            \
    constexpr int ky = (P) >> 1;                                               \
    constexpr int kc = (P) & 1;                                                \
    bf16x8 af[2][3];                                                           \
    _Pragma("unroll") for (int mf = 0; mf < 2; ++mf)                           \
        _Pragma("unroll") for (int kx = 0; kx < 3; ++kx) {                     \
      const int pp = mf * 16 + (lane & 15) + kx;                               \
      const int sl = (kc * 4 + (lane >> 4)) ^ (pp & 7);                        \
      af[mf][kx] =                                                             \
          *(const bf16x8*)(stage + (ky * 34 + pp) * 64 + sl * 8);              \
    }                                                                          \
    _Pragma("unroll") for (int kx = 0; kx < 3; ++kx)                           \
        _Pragma("unroll") for (int mf = 0; mf < 2; ++mf)                       \
            _Pragma("unroll") for (int nf = 0; nf < NF; ++nf)                  \
                acc[mf][nf] = __builtin_amdgcn_mfma_f32_16x16x32_bf16(         \
                    af[mf][kx], BUF[kx][nf], acc[mf][nf], 0, 0, 0);            \
    if (PW) loadB<NF>(PW, NCH, PP6, BUF);                                      \
  }

// ---- conv core: D[32px x NF*16ch x 4 waves] = conv3x3(img, wb), K=576 ------
// Strip rows y..y+2, cols x0..x0+33 staged via global_load_lds; B preloads
// for phases 0..2 issued BEFORE the stage-wait (fly under staging latency).
template <int NF>
__device__ __forceinline__ void conv_core(const u16* __restrict__ img,
                                          const u16* __restrict__ wb,
                                          const int NCH, const int y,
                                          const int x0, const int n0,
                                          u16* stage, f32x4 (&acc)[2][NF]) {
  const int lane = threadIdx.x & 63;
  const int wv = threadIdx.x >> 6;
  const u16* wr = wb + (size_t)(n0 + (lane & 15)) * 64 + ((lane >> 4) * 8);

  bf16x8 B0[3][NF], B1[3][NF], B2[3][NF];
  loadB<NF>(wr, NCH, 0, B0);
  loadB<NF>(wr, NCH, 1, B1);
  loadB<NF>(wr, NCH, 2, B2);

  // stage strip: 3 rows x 34 px x 128B (per row: 4x1KB + 256B)
#pragma unroll
  for (int i = wv; i < 15; i += 4) {
    const int r = i / 5, k = i % 5;
    const u16* g = img + (size_t)(y + r) * PIX + x0 * 64 + k * 512 + lane * 8;
    u16* l = stage + r * 2176 + k * 512;
    if (k < 4 || lane < 16) gll16(g, l);
  }
  asm volatile("s_waitcnt vmcnt(0)" ::: "memory");
  __syncthreads();

  DO_P(0, B0, wr, 3)
  DO_P(1, B1, wr, 4)
  DO_P(2, B2, wr, 5)
  DO_P(3, B0, (const u16*)0, 0)
  DO_P(4, B1, (const u16*)0, 0)
  DO_P(5, B2, (const u16*)0, 0)
}

// ---- weight repack: [o][ci][3][3] f32 -> wcat bf16 [plane][o][ci] ----------
__global__ __launch_bounds__(256) void wprep_k(const float* __restrict__ W,
                                               const float* __restrict__ U,
                                               const float* __restrict__ C,
                                               u16* __restrict__ wcat) {
  int i = blockIdx.x * 256 + threadIdx.x;
  if (i >= 221184) return;
  float v;
  if (i < 110592) {  // W: [9][192][64]
    int plane = i / 12288, rem = i % 12288, o = rem / 64, ci = rem % 64;
    v = W[(size_t)(o * 64 + ci) * 9 + plane];
  } else if (i < 184320) {  // U: [9][128][64]
    int j = i - 110592;
    int plane = j / 8192, rem = j % 8192, o = rem / 64, ci = rem % 64;
    v = U[(size_t)(o * 64 + ci) * 9 + plane];
  } else {  // C: [9][64][64]
    int j = i - 184320;
    int plane = j / 4096, rem = j % 4096, o = rem / 64, ci = rem % 64;
    v = C[(size_t)(o * 64 + ci) * 9 + plane];
  }
  wcat[i] = f2bf(v);
}

// ---- h init: NCHW f32 -> hpad bf16 (swizzled) + hstate f32 NHWC ------------
__global__ __launch_bounds__(256) void hinit_k(const float* __restrict__ h,
                                               u16* __restrict__ hpad,
                                               float* __restrict__ hstate) {
  __shared__ float t[64][57];
  const int y = blockIdx.x, b = blockIdx.y;
  const int tid = threadIdx.x;
  for (int i = tid; i < 64 * 56; i += 256) {
    int ci = i / 56, xx = i % 56;
    t[ci][xx] = h[((size_t)(b * 64) + ci) * 3136 + y * 56 + xx];
  }
  __syncthreads();
  const size_t pb = (size_t)b * PIMG + (size_t)(y + 1) * PIX;
  const size_t sb = ((size_t)(b * 56) + y) * 64;
  for (int i = tid; i < 56 * 64; i += 256) {
    int px = i / 64, ci = i % 64;
    float v = t[ci][px];
    int gx = px + 1;
    hpad[pb + gx * 64 + (((ci >> 3) ^ (gx & 7)) << 3) + (ci & 7)] = f2bf(v);
    hstate[(sb + px) * 64 + ci] = v;
  }
}

// ---- xprep helper: one (b,y,t) row NCHW f32 -> xring bf16 (swizzled) -------
__device__ __forceinline__ void xprep_row(const float* __restrict__ x,
                                          u16* __restrict__ xring, int t,
                                          int b, int y, float (*tt)[57]) {
  const int tid = threadIdx.x;
  for (int i = tid; i < 64 * 56; i += 256) {
    int ci = i / 56, px = i % 56;
    tt[ci][px] = x[((size_t)(b * 16 + t) * 64 + ci) * 3136 + y * 56 + px];
  }
  __syncthreads();
  const size_t pb =
      (size_t)(t & 3) * BIMG + (size_t)b * PIMG + (size_t)(y + 1) * PIX;
  for (int i = tid; i < 56 * 64; i += 256) {
    int px = i / 64, ci = i % 64;
    int gx = px + 1;
    xring[pb + gx * 64 + (((ci >> 3) ^ (gx & 7)) << 3) + (ci & 7)] =
        f2bf(tt[ci][px]);
  }
}

__global__ __launch_bounds__(256) void xprep4_k(const float* __restrict__ x,
                                                u16* __restrict__ xring,
                                                int t0) {
  __shared__ float tt[64][57];
  xprep_row(x, xring, t0 + blockIdx.z, blockIdx.y, blockIdx.x, tt);
}

// ---- convW4: wx(t0..t0+3) = conv(x, W[192]); blocks>=3584 do xprep(t0+4..) -
__global__ __launch_bounds__(256) void convW_k(const float* __restrict__ x,
                                               const u16* __restrict__ xring,
                                               const u16* __restrict__ wcat,
                                               u16* __restrict__ wx, int t0) {
  __shared__ __align__(16) u16 stage[6528];
  const int bid = blockIdx.x;
  if (bid >= 3584) {  // xprep role for next group (t0+4 .. t0+7)
    const int id = bid - 3584;
    const int tt = t0 + 4 + id / 448, rem = id % 448;
    xprep_row(x, (u16*)0 + 0, 0, 0, 0, (float(*)[57])stage);  // placeholder
    return;
  }
  const int x0 = (bid & 1) * 32;
  const int y = (bid >> 1) % 56;
  const int bz = bid / 112;  // 0..31
  const int b = bz & 7, t = t0 + (bz >> 3), slot = t & 3;
  const int lane = threadIdx.x & 63;
  const int n0 = __builtin_amdgcn_readfirstlane((threadIdx.x >> 6) * 48);
  f32x4 acc[2][3];
#pragma unroll
  for (int mf = 0; mf < 2; ++mf)
#pragma unroll
    for (int nf = 0; nf < 3; ++nf) acc[mf][nf] = (f32x4){0.f, 0.f, 0.f, 0.f};
  conv_core<3>(xring + (size_t)slot * BIMG + (size_t)b * PIMG, wcat, 192, y,
               x0, n0, stage, acc);

  const size_t rowb = ((size_t)(b * 4 + slot) * 56 + y) * 64;
#pragma unroll
  for (int mf = 0; mf < 2; ++mf)
#pragma unroll
    for (int nf = 0; nf < 3; ++nf) {
      const int n = n0 + nf * 16 + (lane & 15);
#pragma unroll
      for (int r = 0; r < 4; ++r) {
        const int px = x0 + mf * 16 + 4 * (lane >> 4) + r;
        wx[(rowb + px) * 192 + n] = f2bf(acc[mf][nf][r]);
      }
    }
}

// real xprep fold (separate kernel argument needs xring/x): implemented via
// a dedicated kernel to keep convW_k's signature simple was rejected; instead
// we pass everything and branch above. To keep the placeholder honest we
// re-declare convW_k with the fold below.

// ---- convU: uh = conv(h, U[128]); z=sig(wx_z+uh_z); rh=sig(wx_r+uh_r)*h ----
__global__ __launch_bounds__(256) void convU_k(
    const u16* __restrict__ hpad, const u16* __restrict__ ucat,
    const u16* __restrict__ wx, const float* __restrict__ hstate,
    float* __restrict__ zb, u16* __restrict__ rhpad, int t) {
  __shared__ __align__(16) u16 stage[6528];
  const int x0 = blockIdx.x * 32, y = blockIdx.y, b = blockIdx.z;
  const int slot = t & 3;
  const int lane = threadIdx.x & 63;
  const int n0 = __builtin_amdgcn_readfirstlane((threadIdx.x >> 6) * 32);
  f32x4 acc[2][2];
#pragma unroll
  for (int mf = 0; mf < 2; ++mf)
#pragma unroll
    for (int nf = 0; nf < 2; ++nf) acc[mf][nf] = (f32x4){0.f, 0.f, 0.f, 0.f};
  conv_core<2>(hpad + (size_t)b * PIMG, ucat, 128, y, x0, n0, stage, acc);

  const size_t wrow = ((size_t)(b * 4 + slot) * 56 + y) * 64;
  const size_t rowb = ((size_t)(b * 56) + y) * 64;
#pragma unroll
  for (int mf = 0; mf < 2; ++mf)
#pragma unroll
    for (int nf = 0; nf < 2; ++nf) {
      const int n = n0 + nf * 16 + (lane & 15);
#pragma unroll
      for (int r = 0; r < 4; ++r) {
        const int px = x0 + mf * 16 + 4 * (lane >> 4) + r;
        if (px < 56) {
          float a = bf2f(wx[(wrow + px) * 192 + n]) + acc[mf][nf][r];
          float s = 1.f / (1.f + __expf(-a));
          if (n < 64) {
            zb[(rowb + px) * 64 + n] = s;
          } else {
            const int ci = n - 64;
            float rh = s * hstate[(rowb + px) * 64 + ci];
            const int gx = px + 1;
            rhpad[(size_t)b * PIMG + (size_t)(y + 1) * PIX + gx * 64 +
                  (((ci >> 3) ^ (gx & 7)) << 3) + (ci & 7)] = f2bf(rh);
          }
        }
      }
    }
}

// ---- convC: cc = conv(rh, C[64]); h_new = (1-z)h + z tanh(wx_c + cc) -------
__global__ __launch_bounds__(256) void convC_k(
    const u16* __restrict__ rhpad, const u16* __restrict__ ccat,
    const u16* __restrict__ wx, const float* __restrict__ zb,
    float* __restrict__ hstate, u16* __restrict__ hpad,
    float* __restrict__ out, int t) {
  __shared__ __align__(16) u16 stage[6528];
  __shared__ float ldt[4][16][33];
  const int x0 = blockIdx.x * 32, y = blockIdx.y, b = blockIdx.z;
  const int slot = t & 3;
  const int lane = threadIdx.x & 63;
  const int wv = threadIdx.x >> 6;
  const int n0 = __builtin_amdgcn_readfirstlane(wv * 16);
  f32x4 acc[2][1];
  acc[0][0] = (f32x4){0.f, 0.f, 0.f, 0.f};
  acc[1][0] = (f32x4){0.f, 0.f, 0.f, 0.f};
  conv_core<1>(rhpad + (size_t)b * PIMG, ccat, 64, y, x0, n0, stage, acc);

  const size_t wrow = ((size_t)(b * 4 + slot) * 56 + y) * 64;
  const size_t rowb = ((size_t)(b * 56) + y) * 64;
  const int n = n0 + (lane & 15);
#pragma unroll
  for (int mf = 0; mf < 2; ++mf)
#pragma unroll
    for (int r = 0; r < 4; ++r) {
      const int px = x0 + mf * 16 + 4 * (lane >> 4) + r;
      if (px < 56) {
        float a = bf2f(wx[(wrow + px) * 192 + 128 + n]) + acc[mf][0][r];
        float htil = tanhf(a);
        float z = zb[(rowb + px) * 64 + n];
        float ho = hstate[(rowb + px) * 64 + n];
        float hn = fmaf(z, htil - ho, ho);
        hstate[(rowb + px) * 64 + n] = hn;
        const int gx = px + 1;
        hpad[(size_t)b * PIMG + (size_t)(y + 1) * PIX + gx * 64 +
             (((n >> 3) ^ (gx & 7)) << 3) + (n & 7)] = f2bf(hn);
        ldt[wv][lane & 15][mf * 16 + 4 * (lane >> 4) + r] = hn;
      }
    }
  __syncthreads();
  const int xl = lane & 31;
  const int px = x0 + xl;
  if (px < 56) {
#pragma unroll
    for (int cc = 0; cc < 8; ++cc) {
      const int ch = (lane >> 5) * 8 + cc;
      float v = ldt[wv][ch][xl];
      out[(((size_t)(b * 16 + t)) * 64 + n0 + ch) * 3136 + y * 56 + px] = v;
      if (t == 15)
        out[HL_OFF + ((size_t)(b * 64) + n0 + ch) * 3136 + y * 56 + px] = v;
    }
  }
}

extern "C" void kernel_launch(void* const* d_in, const int* in_sizes, int n_in,
                              void* d_out, int out_size, void* d_ws,
                              size_t ws_size, hipStream_t stream) {
  const float* x = (const float*)d_in[0];
  const float* h = (const float*)d_in[1];
  const float* W = (const float*)d_in[2];
  const float* U = (const float*)d_in[3];
  const float* C = (const float*)d_in[4];
  float* out = (float*)d_out;

  u16* ws_u = (u16*)d_ws;
  u16* xring = ws_u;                     // 4 slots x BIMG = 7,839,744 u16
  u16* hpad = xring + 4 * BIMG;          // 1,959,936
  u16* rhpad = hpad + BIMG;              // 1,959,936
  u16* wcat = rhpad + BIMG;              // 221,184
  u16* wxr = wcat + 221184;              // 8b x 4slot x 56y x 64px x 192
  float* zb = (float*)(wxr + 22020096);  // 1,835,008 f32
  float* hstate = zb + 1835008;          // 1,835,008 f32  (~83 MB total)

  hipMemsetAsync(d_ws, 0, (size_t)6 * BIMG * sizeof(u16), stream);
  wprep_k<<<864, 256, 0, stream>>>(W, U, C, wcat);
  hinit_k<<<dim3(56, 8), 256, 0, stream>>>(h, hpad, hstate);

  dim3 ugrid(2, 56, 8);
  for (int g = 0; g < 4; ++g) {
    const int t0 = g * 4;
    xprep4_k<<<dim3(56, 8, 4), 256, 0, stream>>>(x, xring, t0);
    convW_k<<<3584, 256, 0, stream>>>(x, xring, wcat, wxr, t0);
    for (int tt = 0; tt < 4; ++tt) {
      const int t = t0 + tt;
      convU_k<<<ugrid, 256, 0, stream>>>(hpad, wcat + 110592, wxr, hstate, zb,
                                         rhpad, t);
      convC_k<<<ugrid, 256, 0, stream>>>(rhpad, wcat + 184320, wxr, zb, hstate,
                                         hpad, out, t);
    }
  }
}

// Round 10
// 883.935 us; speedup vs baseline: 1.8192x; 1.3627x over previous
//
#include <hip/hip_runtime.h>
#include <math.h>

// GRU-RCN bf16 MFMA, round-10: GEMM-shaped conv blocks.
//  * B-weights in registers, loaded ONCE per block (wave = 16ch slice, 72 VGPR)
//  * multi-unit blocks: convW 16 units (4t x 4y), convU 4 (y), convC 2 (y)
//  * rolling 1-row LDS ring (8 slots), stage-before-compute, vmcnt(0)/unit
// B=8,T=16,C=Oh=64,HxW=56x56, 3x3 SAME.
// Layouts:
//   padded imgs: bf16 [b][58][66][64ci], 16B ci-slices XOR-swizzled by (col&7)
//   xring: [slot4][b][PIMG]; wx: bf16 [b][slot4][y56][px64][192]
//   wcat: bf16 [plane(ky*3+kx)][o][ci] (W:192, U:128, C:64)
//   zbuf: fp16 [b][y][px64][64]; hstate: f32 [b][y][px64][64]

#define PIX 4224                   // 66*64 u16 per padded row
#define PIMG 244992                // 58*PIX u16 per padded image
#define BIMG ((size_t)8 * PIMG)    // u16 per image set (8 batches)
#define HL_OFF ((size_t)25690112)  // 8*16*64*3136 floats
#define SLOT 2176                  // u16 per ring row slot (34px x 64ci)

typedef unsigned short u16;
typedef __attribute__((ext_vector_type(8))) __bf16 bf16x8;
typedef __attribute__((ext_vector_type(4))) float f32x4;

__device__ __forceinline__ float bf2f(u16 u) {
  unsigned v = ((unsigned)u) << 16;
  float f;
  __builtin_memcpy(&f, &v, 4);
  return f;
}
__device__ __forceinline__ u16 f2bf(float f) {
  unsigned u;
  __builtin_memcpy(&u, &f, 4);
  u = (u + 0x7FFFu + ((u >> 16) & 1u)) >> 16;  // RNE
  return (u16)u;
}
__device__ __forceinline__ void gll16(const u16* g, u16* l) {
  __builtin_amdgcn_global_load_lds(
      (const __attribute__((address_space(1))) void*)g,
      (__attribute__((address_space(3))) void*)l, 16, 0, 0);
}

// ---- stage one padded row (34px x 64ci = 4352B) into ring slot --------------
__device__ __forceinline__ void stage_row(const u16* img, int prow, int x0,
                                          u16* ring, int slot, int lane,
                                          int wv) {
  const u16* g = img + (size_t)prow * PIX + x0 * 64;
  u16* l = ring + slot * SLOT;
  gll16(g + wv * 512 + lane * 8, l + wv * 512);
  if (wv == 0 && lane < 16) gll16(g + 2048 + lane * 8, l + 2048);
}

// ---- full-K weight fragments for one 16ch slice: 18 x bf16x8 (72 VGPR) -----
__device__ __forceinline__ void loadB18(const u16* wr, int NCH,
                                        bf16x8 (&B)[6][3]) {
#pragma unroll
  for (int p = 0; p < 6; ++p) {
    const int ky = p >> 1, kc = p & 1;
#pragma unroll
    for (int kx = 0; kx < 3; ++kx)
      B[p][kx] = *(const bf16x8*)(wr + (size_t)((ky * 3 + kx) * NCH) * 64 +
                                  kc * 32);
  }
}

// ---- one output row: 32px x 16ch, K=576 (36 MFMA), reads ring rows rcb.. ---
__device__ __forceinline__ void conv_unit(const u16* ring, int rcb,
                                          const bf16x8 (&B)[6][3],
                                          f32x4 (&acc)[2], int lane) {
#pragma unroll
  for (int p = 0; p < 6; ++p) {
    const int ky = p >> 1, kc = p & 1;
    const int slot = (rcb + ky) & 7;
    bf16x8 af[2][3];
#pragma unroll
    for (int mf = 0; mf < 2; ++mf)
#pragma unroll
      for (int kx = 0; kx < 3; ++kx) {
        const int pp = mf * 16 + (lane & 15) + kx;
        const int sl = (kc * 4 + (lane >> 4)) ^ (pp & 7);
        af[mf][kx] = *(const bf16x8*)(ring + slot * SLOT + pp * 64 + sl * 8);
      }
#pragma unroll
    for (int kx = 0; kx < 3; ++kx)
#pragma unroll
      for (int mf = 0; mf < 2; ++mf)
        acc[mf] = __builtin_amdgcn_mfma_f32_16x16x32_bf16(af[mf][kx], B[p][kx],
                                                          acc[mf], 0, 0, 0);
  }
}

#define UNIT_SYNC() \
  asm volatile("s_waitcnt vmcnt(0)" ::: "memory"); \
  __syncthreads();

// ---- prep kernels (unchanged) -----------------------------------------------
__global__ __launch_bounds__(256) void wprep_k(const float* __restrict__ W,
                                               const float* __restrict__ U,
                                               const float* __restrict__ C,
                                               u16* __restrict__ wcat) {
  int i = blockIdx.x * 256 + threadIdx.x;
  if (i >= 221184) return;
  float v;
  if (i < 110592) {  // W: [9][192][64]
    int plane = i / 12288, rem = i % 12288, o = rem / 64, ci = rem % 64;
    v = W[(size_t)(o * 64 + ci) * 9 + plane];
  } else if (i < 184320) {  // U: [9][128][64]
    int j = i - 110592;
    int plane = j / 8192, rem = j % 8192, o = rem / 64, ci = rem % 64;
    v = U[(size_t)(o * 64 + ci) * 9 + plane];
  } else {  // C: [9][64][64]
    int j = i - 184320;
    int plane = j / 4096, rem = j % 4096, o = rem / 64, ci = rem % 64;
    v = C[(size_t)(o * 64 + ci) * 9 + plane];
  }
  wcat[i] = f2bf(v);
}

__global__ __launch_bounds__(256) void hinit_k(const float* __restrict__ h,
                                               u16* __restrict__ hpad,
                                               float* __restrict__ hstate) {
  __shared__ float t[64][57];
  const int y = blockIdx.x, b = blockIdx.y;
  const int tid = threadIdx.x;
  for (int i = tid; i < 64 * 56; i += 256) {
    int ci = i / 56, xx = i % 56;
    t[ci][xx] = h[((size_t)(b * 64) + ci) * 3136 + y * 56 + xx];
  }
  __syncthreads();
  const size_t pb = (size_t)b * PIMG + (size_t)(y + 1) * PIX;
  const size_t sb = ((size_t)(b * 56) + y) * 64;
  for (int i = tid; i < 56 * 64; i += 256) {
    int px = i / 64, ci = i % 64;
    float v = t[ci][px];
    int gx = px + 1;
    hpad[pb + gx * 64 + (((ci >> 3) ^ (gx & 7)) << 3) + (ci & 7)] = f2bf(v);
    hstate[(sb + px) * 64 + ci] = v;
  }
}

__global__ __launch_bounds__(256) void xprep4_k(const float* __restrict__ x,
                                                u16* __restrict__ xring,
                                                int t0) {
  __shared__ float tt[64][57];
  const int y = blockIdx.x, b = blockIdx.y, t = t0 + blockIdx.z;
  const int tid = threadIdx.x;
  for (int i = tid; i < 64 * 56; i += 256) {
    int ci = i / 56, px = i % 56;
    tt[ci][px] = x[((size_t)(b * 16 + t) * 64 + ci) * 3136 + y * 56 + px];
  }
  __syncthreads();
  const size_t pb =
      (size_t)(t & 3) * BIMG + (size_t)b * PIMG + (size_t)(y + 1) * PIX;
  for (int i = tid; i < 56 * 64; i += 256) {
    int px = i / 64, ci = i % 64;
    int gx = px + 1;
    xring[pb + gx * 64 + (((ci >> 3) ^ (gx & 7)) << 3) + (ci & 7)] =
        f2bf(tt[ci][px]);
  }
}

// ---- convW: 672 blocks x 16 units (4t x 4y); weights load once --------------
__global__ __launch_bounds__(256, 3) void convW_k(const u16* __restrict__ xring,
                                                  const u16* __restrict__ wcat,
                                                  u16* __restrict__ wx) {
  __shared__ __align__(16) u16 ring[8 * SLOT];
  const int bid = blockIdx.x;
  const int ns = bid / 224;  // 0..2 (64ch block slice)
  const int rem = bid % 224;
  const int b = rem & 7;
  const int r2 = rem >> 3;             // 0..27
  const int x0 = (r2 & 1) * 32;
  const int y0 = (r2 >> 1) * 4;        // 0..52
  const int lane = threadIdx.x & 63, wv = threadIdx.x >> 6;
  const int n0 = ns * 64 + wv * 16;

  const u16* wr = wcat + (size_t)(n0 + (lane & 15)) * 64 + (lane >> 4) * 8;
  bf16x8 B[6][3];
  loadB18(wr, 192, B);

  const u16* img0 = xring + (size_t)b * PIMG;

  // prologue rows rc 0..2 (t=0)
#pragma unroll
  for (int k = 0; k < 3; ++k)
    stage_row(img0, y0 + k, x0, ring, k, lane, wv);

  int S = 3;
#pragma unroll
  for (int u = 0; u < 16; ++u) {
    const int tt = u >> 2, yi = u & 3;
    UNIT_SYNC();
    // stage rows needed by unit u+1 (rc = t*6 + j, row = y0+j of slot-t image)
    const int tgt = (u + 1 < 16) ? (((u + 1) >> 2) * 6 + ((u + 1) & 3) + 2) : 2;
#pragma unroll
    for (; S <= tgt; ++S)
      stage_row(img0 + (size_t)(S / 6) * BIMG, y0 + S % 6, x0, ring, S & 7,
                lane, wv);

    f32x4 acc[2] = {{0.f, 0.f, 0.f, 0.f}, {0.f, 0.f, 0.f, 0.f}};
    conv_unit(ring, tt * 6 + yi, B, acc, lane);

    const int y = y0 + yi;
    const size_t rowb = ((size_t)(b * 4 + tt) * 56 + y) * 64;
    const int n = n0 + (lane & 15);
#pragma unroll
    for (int mf = 0; mf < 2; ++mf)
#pragma unroll
      for (int r = 0; r < 4; ++r) {
        const int px = x0 + mf * 16 + 4 * (lane >> 4) + r;
        wx[(rowb + px) * 192 + n] = f2bf(acc[mf][r]);
      }
  }
}

// ---- convU: 448 blocks x 4 units; z (ns=0) / r*h (ns=1) ---------------------
__global__ __launch_bounds__(256, 3) void convU_k(
    const u16* __restrict__ hpad, const u16* __restrict__ ucat,
    const u16* __restrict__ wx, _Float16* __restrict__ zbuf,
    u16* __restrict__ rhpad, int t) {
  __shared__ __align__(16) u16 ring[8 * SLOT];
  const int bid = blockIdx.x;
  const int ns = bid / 224;  // 0: z-channels, 1: r-channels
  const int rem = bid % 224;
  const int b = rem & 7;
  const int r2 = rem >> 3;
  const int x0 = (r2 & 1) * 32;
  const int y0 = (r2 >> 1) * 4;
  const int lane = threadIdx.x & 63, wv = threadIdx.x >> 6;
  const int n0 = ns * 64 + wv * 16;

  const u16* wr = ucat + (size_t)(n0 + (lane & 15)) * 64 + (lane >> 4) * 8;
  bf16x8 B[6][3];
  loadB18(wr, 128, B);

  const u16* img = hpad + (size_t)b * PIMG;
#pragma unroll
  for (int k = 0; k < 3; ++k) stage_row(img, y0 + k, x0, ring, k, lane, wv);

  const int slott = t & 3;
  int S = 3;
#pragma unroll
  for (int u = 0; u < 4; ++u) {
    UNIT_SYNC();
    const int tgt = (u + 1 < 4) ? (u + 3) : 2;
#pragma unroll
    for (; S <= tgt; ++S)
      stage_row(img, y0 + S, x0, ring, S & 7, lane, wv);

    f32x4 acc[2] = {{0.f, 0.f, 0.f, 0.f}, {0.f, 0.f, 0.f, 0.f}};
    conv_unit(ring, u, B, acc, lane);

    const int y = y0 + u;
    const size_t wrowb = ((size_t)(b * 4 + slott) * 56 + y) * 64;
    const size_t rowb = ((size_t)(b * 56) + y) * 64;
    const int n = n0 + (lane & 15);
#pragma unroll
    for (int mf = 0; mf < 2; ++mf)
#pragma unroll
      for (int r = 0; r < 4; ++r) {
        const int px = x0 + mf * 16 + 4 * (lane >> 4) + r;
        if (px < 56) {
          const float a = bf2f(wx[(wrowb + px) * 192 + n]) + acc[mf][r];
          const float s = 1.f / (1.f + __expf(-a));
          if (ns == 0) {
            zbuf[(rowb + px) * 64 + n] = (_Float16)s;
          } else {
            const int ci = n - 64;
            const int cp = mf * 16 + 4 * (lane >> 4) + r + 1;  // strip col
            const int slotc = (u + 1) & 7;                     // center row
            const float hv =
                bf2f(ring[slotc * SLOT + cp * 64 +
                          (((ci >> 3) ^ (cp & 7)) << 3) + (ci & 7)]);
            const int gx = px + 1;
            rhpad[(size_t)b * PIMG + (size_t)(y + 1) * PIX + gx * 64 +
                  (((ci >> 3) ^ (gx & 7)) << 3) + (ci & 7)] = f2bf(s * hv);
          }
        }
      }
  }
}

// ---- convC: 448 blocks x 2 units; h' = (1-z)h + z tanh(wx_c + conv(rh,C)) --
__global__ __launch_bounds__(256, 3) void convC_k(
    const u16* __restrict__ rhpad, const u16* __restrict__ ccat,
    const u16* __restrict__ wx, const _Float16* __restrict__ zbuf,
    float* __restrict__ hstate, u16* __restrict__ hpad,
    float* __restrict__ out, int t) {
  __shared__ __align__(16) u16 ring[8 * SLOT];
  __shared__ float ldt[4][16][33];
  const int bid = blockIdx.x;
  const int b = bid & 7;
  const int r2 = bid >> 3;             // 0..55
  const int x0 = (r2 & 1) * 32;
  const int y0 = (r2 >> 1) * 2;        // 0..54
  const int lane = threadIdx.x & 63, wv = threadIdx.x >> 6;
  const int n0 = wv * 16;

  const u16* wr = ccat + (size_t)(n0 + (lane & 15)) * 64 + (lane >> 4) * 8;
  bf16x8 B[6][3];
  loadB18(wr, 64, B);

  const u16* img = rhpad + (size_t)b * PIMG;
#pragma unroll
  for (int k = 0; k < 3; ++k) stage_row(img, y0 + k, x0, ring, k, lane, wv);

  const int slott = t & 3;
#pragma unroll
  for (int u = 0; u < 2; ++u) {
    UNIT_SYNC();
    if (u == 0) stage_row(img, y0 + 3, x0, ring, 3, lane, wv);

    f32x4 acc[2] = {{0.f, 0.f, 0.f, 0.f}, {0.f, 0.f, 0.f, 0.f}};
    conv_unit(ring, u, B, acc, lane);

    const int y = y0 + u;
    const size_t wrowb = ((size_t)(b * 4 + slott) * 56 + y) * 64;
    const size_t rowb = ((size_t)(b * 56) + y) * 64;
    const int n = n0 + (lane & 15);
    float hnv[2][4];
#pragma unroll
    for (int mf = 0; mf < 2; ++mf)
#pragma unroll
      for (int r = 0; r < 4; ++r) {
        const int px = x0 + mf * 16 + 4 * (lane >> 4) + r;
        hnv[mf][r] = 0.f;
        if (px < 56) {
          const float a = bf2f(wx[(wrowb + px) * 192 + 128 + n]) + acc[mf][r];
          const float htil = tanhf(a);
          const float z = (float)zbuf[(rowb + px) * 64 + n];
          const float ho = hstate[(rowb + px) * 64 + n];
          const float hn = fmaf(z, htil - ho, ho);
          hstate[(rowb + px) * 64 + n] = hn;
          const int gx = px + 1;
          hpad[(size_t)b * PIMG + (size_t)(y + 1) * PIX + gx * 64 +
               (((n >> 3) ^ (gx & 7)) << 3) + (n & 7)] = f2bf(hn);
          hnv[mf][r] = hn;
        }
      }
    __syncthreads();
#pragma unroll
    for (int mf = 0; mf < 2; ++mf)
#pragma unroll
      for (int r = 0; r < 4; ++r)
        ldt[wv][lane & 15][mf * 16 + 4 * (lane >> 4) + r] = hnv[mf][r];
    __syncthreads();
    const int xl = lane & 31;
    const int px = x0 + xl;
    if (px < 56) {
#pragma unroll
      for (int cc = 0; cc < 8; ++cc) {
        const int ch = (lane >> 5) * 8 + cc;
        const float v = ldt[wv][ch][xl];
        out[(((size_t)(b * 16 + t)) * 64 + n0 + ch) * 3136 + y * 56 + px] = v;
        if (t == 15)
          out[HL_OFF + ((size_t)(b * 64) + n0 + ch) * 3136 + y * 56 + px] = v;
      }
    }
  }
}

extern "C" void kernel_launch(void* const* d_in, const int* in_sizes, int n_in,
                              void* d_out, int out_size, void* d_ws,
                              size_t ws_size, hipStream_t stream) {
  const float* x = (const float*)d_in[0];
  const float* h = (const float*)d_in[1];
  const float* W = (const float*)d_in[2];
  const float* U = (const float*)d_in[3];
  const float* C = (const float*)d_in[4];
  float* out = (float*)d_out;

  u16* ws_u = (u16*)d_ws;
  u16* xring = ws_u;                     // 4 slots x BIMG
  u16* hpad = xring + 4 * BIMG;          // BIMG
  u16* rhpad = hpad + BIMG;              // BIMG
  u16* wcat = rhpad + BIMG;              // 221,184
  u16* wxr = wcat + 221184;              // 8b x 4slot x 56y x 64px x 192
  _Float16* zbuf = (_Float16*)(wxr + 22020096);  // 1,835,008 fp16
  float* hstate = (float*)(zbuf + 1835008);      // 1,835,008 f32

  hipMemsetAsync(d_ws, 0, (size_t)6 * BIMG * sizeof(u16), stream);
  wprep_k<<<864, 256, 0, stream>>>(W, U, C, wcat);
  hinit_k<<<dim3(56, 8), 256, 0, stream>>>(h, hpad, hstate);

  for (int g = 0; g < 4; ++g) {
    const int t0 = g * 4;
    xprep4_k<<<dim3(56, 8, 4), 256, 0, stream>>>(x, xring, t0);
    convW_k<<<672, 256, 0, stream>>>(xring, wcat, wxr);
    for (int tt = 0; tt < 4; ++tt) {
      const int t = t0 + tt;
      convU_k<<<448, 256, 0, stream>>>(hpad, wcat + 110592, wxr, zbuf, rhpad,
                                       t);
      convC_k<<<448, 256, 0, stream>>>(rhpad, wcat + 184320, wxr, zbuf, hstate,
                                       hpad, out, t);
    }
  }
}

// Round 11
// 813.651 us; speedup vs baseline: 1.9763x; 1.0864x over previous
//
#include <hip/hip_runtime.h>
#include <math.h>

// GRU-RCN bf16 MFMA, round-11: r10's GEMM-shaped blocks + x-path co-dispatch
// + fp16 hstate.  B=8,T=16,C=Oh=64,HxW=56x56, 3x3 SAME.
// Per step t:
//   convUW: blocks<448 convU(t) -> z, r*h ; blocks>=448 convW(t+1) -> wx ring
//   convCX: blocks<448 convC(t) -> h', out ; blocks>=448 xprep(t+2)
// Layouts:
//   padded imgs (xpad[2]/hpad/rhpad): bf16 [b][58][66][64ci], 16B ci-slices
//     XOR-swizzled by (col&7) -> conflict-free ds_read_b128.
//   wcat: bf16 [plane(ky*3+kx)][o][ci] (W:192, U:128, C:64)
//   wx[2]: bf16 [b][y56][px64][192]; zbuf/hstate: fp16 [b][y][px64][64]

#define PIX 4224                   // 66*64 u16 per padded row
#define PIMG 244992                // 58*PIX u16 per padded image
#define BIMG ((size_t)8 * PIMG)    // u16 per image set (8 batches)
#define WXS ((size_t)5505024)      // u16 per wx slot: 8*56*64*192
#define HL_OFF ((size_t)25690112)  // 8*16*64*3136 floats
#define SLOT 2176                  // u16 per ring row slot (34px x 64ci)

typedef unsigned short u16;
typedef __attribute__((ext_vector_type(8))) __bf16 bf16x8;
typedef __attribute__((ext_vector_type(4))) float f32x4;

__device__ __forceinline__ float bf2f(u16 u) {
  unsigned v = ((unsigned)u) << 16;
  float f;
  __builtin_memcpy(&f, &v, 4);
  return f;
}
__device__ __forceinline__ u16 f2bf(float f) {
  unsigned u;
  __builtin_memcpy(&u, &f, 4);
  u = (u + 0x7FFFu + ((u >> 16) & 1u)) >> 16;  // RNE
  return (u16)u;
}
__device__ __forceinline__ void gll16(const u16* g, u16* l) {
  __builtin_amdgcn_global_load_lds(
      (const __attribute__((address_space(1))) void*)g,
      (__attribute__((address_space(3))) void*)l, 16, 0, 0);
}

// ---- stage one padded row (34px x 64ci = 4352B) into ring slot --------------
__device__ __forceinline__ void stage_row(const u16* img, int prow, int x0,
                                          u16* ring, int slot, int lane,
                                          int wv) {
  const u16* g = img + (size_t)prow * PIX + x0 * 64;
  u16* l = ring + slot * SLOT;
  gll16(g + wv * 512 + lane * 8, l + wv * 512);
  if (wv == 0 && lane < 16) gll16(g + 2048 + lane * 8, l + 2048);
}

// ---- full-K weight fragments for one 16ch slice: 18 x bf16x8 ---------------
__device__ __forceinline__ void loadB18(const u16* wr, int NCH,
                                        bf16x8 (&B)[6][3]) {
#pragma unroll
  for (int p = 0; p < 6; ++p) {
    const int ky = p >> 1, kc = p & 1;
#pragma unroll
    for (int kx = 0; kx < 3; ++kx)
      B[p][kx] = *(const bf16x8*)(wr + (size_t)((ky * 3 + kx) * NCH) * 64 +
                                  kc * 32);
  }
}

// ---- one output row: 32px x 16ch, K=576 (36 MFMA) --------------------------
__device__ __forceinline__ void conv_unit(const u16* ring, int rcb,
                                          const bf16x8 (&B)[6][3],
                                          f32x4 (&acc)[2], int lane) {
#pragma unroll
  for (int p = 0; p < 6; ++p) {
    const int ky = p >> 1, kc = p & 1;
    const int slot = (rcb + ky) & 7;
    bf16x8 af[2][3];
#pragma unroll
    for (int mf = 0; mf < 2; ++mf)
#pragma unroll
      for (int kx = 0; kx < 3; ++kx) {
        const int pp = mf * 16 + (lane & 15) + kx;
        const int sl = (kc * 4 + (lane >> 4)) ^ (pp & 7);
        af[mf][kx] = *(const bf16x8*)(ring + slot * SLOT + pp * 64 + sl * 8);
      }
#pragma unroll
    for (int kx = 0; kx < 3; ++kx)
#pragma unroll
      for (int mf = 0; mf < 2; ++mf)
        acc[mf] = __builtin_amdgcn_mfma_f32_16x16x32_bf16(af[mf][kx], B[p][kx],
                                                          acc[mf], 0, 0, 0);
  }
}

#define UNIT_SYNC() \
  asm volatile("s_waitcnt vmcnt(0)" ::: "memory"); \
  __syncthreads();

// ---- convW role: id in [0,336): 8 y-units, one timestep --------------------
__device__ __forceinline__ void do_convW(const u16* __restrict__ xslot,
                                         const u16* __restrict__ wcat,
                                         u16* __restrict__ wx, int id,
                                         u16* ring) {
  const int ns = id / 112;
  const int rem = id % 112;
  const int b = rem & 7;
  const int v = rem >> 3;  // 0..13
  const int x0 = (v & 1) * 32;
  const int y0 = (v >> 1) * 8;  // 0..48
  const int lane = threadIdx.x & 63, wv = threadIdx.x >> 6;
  const int n0 = ns * 64 + wv * 16;

  const u16* wr = wcat + (size_t)(n0 + (lane & 15)) * 64 + (lane >> 4) * 8;
  bf16x8 B[6][3];
  loadB18(wr, 192, B);

  const u16* img = xslot + (size_t)b * PIMG;
#pragma unroll
  for (int k = 0; k < 3; ++k) stage_row(img, y0 + k, x0, ring, k, lane, wv);

  int S = 3;
#pragma unroll
  for (int u = 0; u < 8; ++u) {
    UNIT_SYNC();
    const int tgt = (u + 1 < 8) ? (u + 3) : 2;
#pragma unroll
    for (; S <= tgt; ++S)
      stage_row(img, y0 + S, x0, ring, S & 7, lane, wv);

    f32x4 acc[2] = {{0.f, 0.f, 0.f, 0.f}, {0.f, 0.f, 0.f, 0.f}};
    conv_unit(ring, u, B, acc, lane);

    const int y = y0 + u;
    const size_t rowb = ((size_t)(b * 56) + y) * 64;
    const int n = n0 + (lane & 15);
#pragma unroll
    for (int mf = 0; mf < 2; ++mf)
#pragma unroll
      for (int r = 0; r < 4; ++r) {
        const int px = x0 + mf * 16 + 4 * (lane >> 4) + r;
        wx[(rowb + px) * 192 + n] = f2bf(acc[mf][r]);
      }
  }
}

// ---- xprep row: NCHW f32 -> padded bf16 slot (swizzled) --------------------
__device__ __forceinline__ void xprep_row(const float* __restrict__ x,
                                          u16* __restrict__ dst, int t, int b,
                                          int y, float (*tx)[57]) {
  const int tid = threadIdx.x;
  for (int i = tid; i < 64 * 56; i += 256) {
    int ci = i / 56, px = i % 56;
    tx[ci][px] = x[((size_t)(b * 16 + t) * 64 + ci) * 3136 + y * 56 + px];
  }
  __syncthreads();
  const size_t pb = (size_t)b * PIMG + (size_t)(y + 1) * PIX;
  for (int i = tid; i < 56 * 64; i += 256) {
    int px = i / 64, ci = i % 64;
    int gx = px + 1;
    dst[pb + gx * 64 + (((ci >> 3) ^ (gx & 7)) << 3) + (ci & 7)] =
        f2bf(tx[ci][px]);
  }
}

// ---- prep kernels -----------------------------------------------------------
__global__ __launch_bounds__(256) void wprep_k(const float* __restrict__ W,
                                               const float* __restrict__ U,
                                               const float* __restrict__ C,
                                               u16* __restrict__ wcat) {
  int i = blockIdx.x * 256 + threadIdx.x;
  if (i >= 221184) return;
  float v;
  if (i < 110592) {  // W: [9][192][64]
    int plane = i / 12288, rem = i % 12288, o = rem / 64, ci = rem % 64;
    v = W[(size_t)(o * 64 + ci) * 9 + plane];
  } else if (i < 184320) {  // U: [9][128][64]
    int j = i - 110592;
    int plane = j / 8192, rem = j % 8192, o = rem / 64, ci = rem % 64;
    v = U[(size_t)(o * 64 + ci) * 9 + plane];
  } else {  // C: [9][64][64]
    int j = i - 184320;
    int plane = j / 4096, rem = j % 4096, o = rem / 64, ci = rem % 64;
    v = C[(size_t)(o * 64 + ci) * 9 + plane];
  }
  wcat[i] = f2bf(v);
}

__global__ __launch_bounds__(256) void hinit_k(const float* __restrict__ h,
                                               u16* __restrict__ hpad,
                                               _Float16* __restrict__ hstate) {
  __shared__ float t[64][57];
  const int y = blockIdx.x, b = blockIdx.y;
  const int tid = threadIdx.x;
  for (int i = tid; i < 64 * 56; i += 256) {
    int ci = i / 56, xx = i % 56;
    t[ci][xx] = h[((size_t)(b * 64) + ci) * 3136 + y * 56 + xx];
  }
  __syncthreads();
  const size_t pb = (size_t)b * PIMG + (size_t)(y + 1) * PIX;
  const size_t sb = ((size_t)(b * 56) + y) * 64;
  for (int i = tid; i < 56 * 64; i += 256) {
    int px = i / 64, ci = i % 64;
    float v = t[ci][px];
    int gx = px + 1;
    hpad[pb + gx * 64 + (((ci >> 3) ^ (gx & 7)) << 3) + (ci & 7)] = f2bf(v);
    hstate[(sb + px) * 64 + ci] = (_Float16)v;
  }
}

__global__ __launch_bounds__(256) void xprep01_k(const float* __restrict__ x,
                                                 u16* __restrict__ x0,
                                                 u16* __restrict__ x1) {
  __shared__ float tt[64][57];
  const int t = blockIdx.y;
  xprep_row(x, t ? x1 : x0, t, blockIdx.x & 7, blockIdx.x >> 3, tt);
}

__global__ __launch_bounds__(256, 3) void convW0_k(const u16* __restrict__ xs,
                                                   const u16* __restrict__ wcat,
                                                   u16* __restrict__ wx) {
  __shared__ __align__(16) u16 ring[8 * SLOT];
  do_convW(xs, wcat, wx, blockIdx.x, ring);
}

// ---- convUW: convU(t) [bid<448] || convW(t+1) [bid>=448] --------------------
__global__ __launch_bounds__(256, 3) void convUW_k(
    const u16* __restrict__ hpad, const u16* __restrict__ xpad_n,
    const u16* __restrict__ wcat, const u16* __restrict__ wx_c,
    u16* __restrict__ wx_n, _Float16* __restrict__ zbuf,
    u16* __restrict__ rhpad) {
  __shared__ __align__(16) u16 ring[8 * SLOT];
  const int bid = blockIdx.x;
  if (bid >= 448) {
    do_convW(xpad_n, wcat, wx_n, bid - 448, ring);
    return;
  }
  const int ns = bid / 224;  // 0: z-channels, 1: r-channels
  const int rem = bid % 224;
  const int b = rem & 7;
  const int r2 = rem >> 3;
  const int x0 = (r2 & 1) * 32;
  const int y0 = (r2 >> 1) * 4;
  const int lane = threadIdx.x & 63, wv = threadIdx.x >> 6;
  const int n0 = ns * 64 + wv * 16;

  const u16* wr =
      wcat + 110592 + (size_t)(n0 + (lane & 15)) * 64 + (lane >> 4) * 8;
  bf16x8 B[6][3];
  loadB18(wr, 128, B);

  const u16* img = hpad + (size_t)b * PIMG;
#pragma unroll
  for (int k = 0; k < 3; ++k) stage_row(img, y0 + k, x0, ring, k, lane, wv);

  int S = 3;
#pragma unroll
  for (int u = 0; u < 4; ++u) {
    UNIT_SYNC();
    const int tgt = (u + 1 < 4) ? (u + 3) : 2;
#pragma unroll
    for (; S <= tgt; ++S)
      stage_row(img, y0 + S, x0, ring, S & 7, lane, wv);

    f32x4 acc[2] = {{0.f, 0.f, 0.f, 0.f}, {0.f, 0.f, 0.f, 0.f}};
    conv_unit(ring, u, B, acc, lane);

    const int y = y0 + u;
    const size_t rowb = ((size_t)(b * 56) + y) * 64;
    const int n = n0 + (lane & 15);
#pragma unroll
    for (int mf = 0; mf < 2; ++mf)
#pragma unroll
      for (int r = 0; r < 4; ++r) {
        const int px = x0 + mf * 16 + 4 * (lane >> 4) + r;
        if (px < 56) {
          const float a = bf2f(wx_c[(rowb + px) * 192 + n]) + acc[mf][r];
          const float s = 1.f / (1.f + __expf(-a));
          if (ns == 0) {
            zbuf[(rowb + px) * 64 + n] = (_Float16)s;
          } else {
            const int ci = n - 64;
            const int cp = mf * 16 + 4 * (lane >> 4) + r + 1;  // strip col
            const int slotc = (u + 1) & 7;                     // center row
            const float hv =
                bf2f(ring[slotc * SLOT + cp * 64 +
                          (((ci >> 3) ^ (cp & 7)) << 3) + (ci & 7)]);
            const int gx = px + 1;
            rhpad[(size_t)b * PIMG + (size_t)(y + 1) * PIX + gx * 64 +
                  (((ci >> 3) ^ (gx & 7)) << 3) + (ci & 7)] = f2bf(s * hv);
          }
        }
      }
  }
}

// ---- convCX: convC(t) [bid<448] || xprep(t+2) [bid>=448] --------------------
__global__ __launch_bounds__(256, 3) void convCX_k(
    const float* __restrict__ x, u16* __restrict__ xpad_w,
    const u16* __restrict__ rhpad, const u16* __restrict__ wcat,
    const u16* __restrict__ wx_c, const _Float16* __restrict__ zbuf,
    _Float16* __restrict__ hstate, u16* __restrict__ hpad,
    float* __restrict__ out, int t) {
  __shared__ __align__(16) u16 ring[8 * SLOT];
  __shared__ float ldt[4][16][33];
  const int bid = blockIdx.x;
  if (bid >= 448) {
    const int id = bid - 448;
    xprep_row(x, xpad_w, t + 2, id & 7, id >> 3, (float(*)[57])ring);
    return;
  }
  const int b = bid & 7;
  const int r2 = bid >> 3;       // 0..55
  const int x0 = (r2 & 1) * 32;
  const int y0 = (r2 >> 1) * 2;  // 0..54
  const int lane = threadIdx.x & 63, wv = threadIdx.x >> 6;
  const int n0 = wv * 16;

  const u16* wr =
      wcat + 184320 + (size_t)(n0 + (lane & 15)) * 64 + (lane >> 4) * 8;
  bf16x8 B[6][3];
  loadB18(wr, 64, B);

  const u16* img = rhpad + (size_t)b * PIMG;
#pragma unroll
  for (int k = 0; k < 3; ++k) stage_row(img, y0 + k, x0, ring, k, lane, wv);

#pragma unroll
  for (int u = 0; u < 2; ++u) {
    UNIT_SYNC();
    if (u == 0) stage_row(img, y0 + 3, x0, ring, 3, lane, wv);

    f32x4 acc[2] = {{0.f, 0.f, 0.f, 0.f}, {0.f, 0.f, 0.f, 0.f}};
    conv_unit(ring, u, B, acc, lane);

    const int y = y0 + u;
    const size_t rowb = ((size_t)(b * 56) + y) * 64;
    const int n = n0 + (lane & 15);
    float hnv[2][4];
#pragma unroll
    for (int mf = 0; mf < 2; ++mf)
#pragma unroll
      for (int r = 0; r < 4; ++r) {
        const int px = x0 + mf * 16 + 4 * (lane >> 4) + r;
        hnv[mf][r] = 0.f;
        if (px < 56) {
          const float a = bf2f(wx_c[(rowb + px) * 192 + 128 + n]) + acc[mf][r];
          const float htil = tanhf(a);
          const float z = (float)zbuf[(rowb + px) * 64 + n];
          const float ho = (float)hstate[(rowb + px) * 64 + n];
          const float hn = fmaf(z, htil - ho, ho);
          hstate[(rowb + px) * 64 + n] = (_Float16)hn;
          const int gx = px + 1;
          hpad[(size_t)b * PIMG + (size_t)(y + 1) * PIX + gx * 64 +
               (((n >> 3) ^ (gx & 7)) << 3) + (n & 7)] = f2bf(hn);
          hnv[mf][r] = hn;
        }
      }
    __syncthreads();
#pragma unroll
    for (int mf = 0; mf < 2; ++mf)
#pragma unroll
      for (int r = 0; r < 4; ++r)
        ldt[wv][lane & 15][mf * 16 + 4 * (lane >> 4) + r] = hnv[mf][r];
    __syncthreads();
    const int xl = lane & 31;
    const int px = x0 + xl;
    if (px < 56) {
#pragma unroll
      for (int cc = 0; cc < 8; ++cc) {
        const int ch = (lane >> 5) * 8 + cc;
        const float v = ldt[wv][ch][xl];
        out[(((size_t)(b * 16 + t)) * 64 + n0 + ch) * 3136 + y * 56 + px] = v;
        if (t == 15)
          out[HL_OFF + ((size_t)(b * 64) + n0 + ch) * 3136 + y * 56 + px] = v;
      }
    }
  }
}

extern "C" void kernel_launch(void* const* d_in, const int* in_sizes, int n_in,
                              void* d_out, int out_size, void* d_ws,
                              size_t ws_size, hipStream_t stream) {
  const float* x = (const float*)d_in[0];
  const float* h = (const float*)d_in[1];
  const float* W = (const float*)d_in[2];
  const float* U = (const float*)d_in[3];
  const float* C = (const float*)d_in[4];
  float* out = (float*)d_out;

  u16* ws_u = (u16*)d_ws;
  u16* xpad = ws_u;                               // 2 slots x BIMG
  u16* hpad = xpad + 2 * BIMG;                    // BIMG
  u16* rhpad = hpad + BIMG;                       // BIMG
  u16* wcat = rhpad + BIMG;                       // 221,184
  u16* wxr = wcat + 221184;                       // 2 slots x WXS
  _Float16* zbuf = (_Float16*)(wxr + 2 * WXS);    // 1,835,008 fp16
  _Float16* hstate = zbuf + 1835008;              // 1,835,008 fp16

  // zero the 4 padded images (borders must stay 0)
  hipMemsetAsync(d_ws, 0, (size_t)4 * BIMG * sizeof(u16), stream);
  wprep_k<<<864, 256, 0, stream>>>(W, U, C, wcat);
  hinit_k<<<dim3(56, 8), 256, 0, stream>>>(h, hpad, hstate);
  xprep01_k<<<dim3(448, 2), 256, 0, stream>>>(x, xpad, xpad + BIMG);
  convW0_k<<<336, 256, 0, stream>>>(xpad, wcat, wxr);  // wx(0) -> slot 0

  for (int t = 0; t < 16; ++t) {
    u16* xn = xpad + (size_t)((t + 1) & 1) * BIMG;   // x(t+1) image
    u16* xw = xpad + (size_t)(t & 1) * BIMG;         // xprep(t+2) target
    const u16* wxc = wxr + (size_t)(t & 1) * WXS;    // wx(t)
    u16* wxn = wxr + (size_t)((t + 1) & 1) * WXS;    // wx(t+1)

    const int nbA = 448 + ((t < 15) ? 336 : 0);
    convUW_k<<<nbA, 256, 0, stream>>>(hpad, xn, wcat, wxc, wxn, zbuf, rhpad);

    const int nbB = 448 + ((t < 14) ? 448 : 0);
    convCX_k<<<nbB, 256, 0, stream>>>(x, xw, rhpad, wcat, wxc, zbuf, hstate,
                                      hpad, out, t);
  }
}